// Round 6
// baseline (89.422 us; speedup 1.0000x reference)
//
#include <hip/hip_runtime.h>
#include <math.h>

#define EEG_CH 64
#define WIN    128
#define KW     9
#define OUTW   120
#define NOUT   10
#define CWP    12           // padded cwl row stride (48B, 16B-aligned rows)

// cross-block handoff in module globals (d_ws not used):
// g_msum[o*2+h]; g_ctr = monotonic counter, 10 increments/launch (1 per block).
__device__ float        g_msum[2 * NOUT];
__device__ unsigned int g_ctr = 0;

__device__ __forceinline__ float readlane_f(float v, int l) {
    return __int_as_float(__builtin_amdgcn_readlane(__float_as_int(v), l));
}

// One fused kernel node: block o = output channel, 16 waves, 1 block/CU.
// No bulk LDS staging: conv reads x straight from global (coalesced float2,
// L1-warmed by the phase-A norm pass); SE waves hold w1/w2 rows in registers
// (loaded at phase A start). SE chain (waves 8,9) hidden under conv dots
// (waves 0-7). Tail = verified count-to-10 atomic handshake.
__launch_bounds__(1024)
__global__ void cnn_fused(const float* __restrict__ xg,
                          const float* __restrict__ w1g, const float* __restrict__ b1g,
                          const float* __restrict__ w2g, const float* __restrict__ b2g,
                          const float* __restrict__ cwg, const float* __restrict__ cbg,
                          const float* __restrict__ f1w, const float* __restrict__ f1b,
                          const float* __restrict__ f2w, const float* __restrict__ f2b,
                          float* __restrict__ out)
{
    __shared__ float cwl[64 * CWP];   // conv weights for this o, padded rows
    __shared__ float rnorm[66];
    __shared__ float nums[2];
    __shared__ float sef[128];        // se_flat [h][i]
    __shared__ float part[8][2][OUTW];// per-(chunk, h) partial pre-relu sums
    __shared__ float msh[2];
    __shared__ int   sflag;
    __shared__ float msums[2 * NOUT];
    __shared__ float fcnl[232];       // f1w[0..199] f1b[200..209] f2w[210..229] f2b[230..231]

    const int tid  = threadIdx.x;
    const int wv   = tid >> 6;        // 0..15
    const int lane = tid & 63;
    const int o    = blockIdx.x;

    // conv mapping: waves 0-7 each own an 8-channel chunk (both h)
    const int chbase = (wv & 7) * 8;

    // ---- phase A: weight prefetch + norms (no bulk LDS staging) ----
    // SE waves: w1/w2 row j -> registers (contiguous 256B/lane), b1/b2 prefetch
    float4 w1r[16], w2r[16];
    float  b1v = 0.f, b2v = 0.f;
    if (wv == 8 || wv == 9) {
        const float* __restrict__ r1 = w1g + lane * 64;
        const float* __restrict__ r2 = w2g + lane * 64;
        #pragma unroll
        for (int q = 0; q < 16; ++q) w1r[q] = *(const float4*)(r1 + 4 * q);
        #pragma unroll
        for (int q = 0; q < 16; ++q) w2r[q] = *(const float4*)(r2 + 4 * q);
        b1v = b1g[lane];
        b2v = b2g[lane];
    }
    // conv waves: stage conv weights for this o (576 floats, padded rows)
    if (wv < 8) {
        for (int t = tid; t < 576; t += 512)
            cwl[(t / KW) * CWP + (t % KW)] = cwg[o * (EEG_CH * KW) + t];
    }
    // waves 10-13: FCN params -> LDS (hidden under norms)
    if (tid >= 640 && tid < 872) {
        const int t = tid - 640;
        float v;
        if      (t < 200) v = f1w[t];
        else if (t < 210) v = f1b[t - 200];
        else if (t < 230) v = f2w[t - 210];
        else              v = f2b[t - 230];
        fcnl[t] = v;
    }
    // row norms over the 14 non-SE waves (same per-row reduction tree);
    // this pass also warms L1 with every x row for the phase-B conv reads
    if (wv < 8 || wv >= 10) {
        const int wvn = (wv < 8) ? wv : wv - 2;
        for (int row = wvn; row < 66; row += 14) {
            const float v0 = xg[row * WIN + lane];
            const float v1 = xg[row * WIN + 64 + lane];
            float s = v0 * v0 + v1 * v1;
            for (int off = 32; off > 0; off >>= 1) s += __shfl_xor(s, off, 64);
            if (lane == 0) rnorm[row] = sqrtf(s);
        }
    }
    if (wv < 2) {
        const int wrow = (wv == 0) ? 0 : 65;
        float p = xg[WIN + lane]      * xg[wrow * WIN + lane]
                + xg[WIN + 64 + lane] * xg[wrow * WIN + 64 + lane];
        for (int off = 32; off > 0; off >>= 1) p += __shfl_xor(p, off, 64);
        if (lane == 0) nums[wv] = p;
    }
    __syncthreads();

    // ---- phase B || C-dots: SE chain (waves 8,9) hidden under conv dots ----
    const int wbase = (lane < 60) ? 2 * lane : 116;   // lanes 60-63 redundant
    float p0a[8], p1a[8];
    if (wv < 8) {
        // unweighted per-channel dots straight from global (coalesced, L1-hot)
        #pragma unroll
        for (int ii = 0; ii < 8; ++ii) {
            const int i = chbase + ii;
            const float2* xp = (const float2*)(xg + (i + 1) * WIN + wbase);
            const float2 x0 = xp[0], x1 = xp[1], x2 = xp[2], x3 = xp[3], x4 = xp[4];
            const float xw[10] = { x0.x, x0.y, x1.x, x1.y, x2.x, x2.y,
                                   x3.x, x3.y, x4.x, x4.y };
            // weights via uniform-address LDS reads (wave-wide broadcast)
            const float4 wa = *(const float4*)(cwl + i * CWP);
            const float4 wb = *(const float4*)(cwl + i * CWP + 4);
            const float  w8 = cwl[i * CWP + 8];
            const float wk[KW] = { wa.x, wa.y, wa.z, wa.w,
                                   wb.x, wb.y, wb.z, wb.w, w8 };
            float p0 = 0.f, p1 = 0.f;
            #pragma unroll
            for (int k = 0; k < KW; ++k) {
                p0 += xw[k]     * wk[k];
                p1 += xw[k + 1] * wk[k];
            }
            p0a[ii] = p0;
            p1a[ii] = p1;
        }
    } else if (wv < 10) {
        // SE MLP for r = wv-8; weights from registers (same ascending i order)
        const int r = wv - 8, j = lane;
        const float er = nums[r] / (rnorm[j + 1] * (r == 0 ? rnorm[0] : rnorm[65]));
        float acc = b1v;
        #pragma unroll
        for (int q = 0; q < 16; ++q) {
            const float4 w = w1r[q];
            acc += readlane_f(er, 4 * q + 0) * w.x;
            acc += readlane_f(er, 4 * q + 1) * w.y;
            acc += readlane_f(er, 4 * q + 2) * w.z;
            acc += readlane_f(er, 4 * q + 3) * w.w;
        }
        const float hv = tanhf(acc);
        float acc2 = b2v;
        #pragma unroll
        for (int q = 0; q < 16; ++q) {
            const float4 w = w2r[q];
            acc2 += readlane_f(hv, 4 * q + 0) * w.x;
            acc2 += readlane_f(hv, 4 * q + 1) * w.y;
            acc2 += readlane_f(hv, 4 * q + 2) * w.z;
            acc2 += readlane_f(hv, 4 * q + 3) * w.w;
        }
        const float sg = 1.f / (1.f + expf(-acc2));
        float mx = sg;
        for (int off = 32; off > 0; off >>= 1) mx = fmaxf(mx, __shfl_xor(mx, off, 64));
        const float e = expf(sg - mx);
        float ss = e;
        for (int off = 32; off > 0; off >>= 1) ss += __shfl_xor(ss, off, 64);
        sef[r * 64 + j] = e / ss;
    }
    __syncthreads();

    // ---- C2: weight dots by se (same ascending channel order), write part ----
    if (wv < 8) {
        float q00 = 0.f, q01 = 0.f;   // h=0 accumulators (pos w, w+1)
        float q10 = 0.f, q11 = 0.f;   // h=1 accumulators
        #pragma unroll
        for (int ii = 0; ii < 8; ++ii) {
            const float s0 = sef[chbase + ii];        // uniform LDS broadcast
            const float s1 = sef[64 + chbase + ii];
            q00 += s0 * p0a[ii];  q01 += s0 * p1a[ii];
            q10 += s1 * p0a[ii];  q11 += s1 * p1a[ii];
        }
        if (lane < 60) {
            *(float2*)(&part[wv][0][wbase]) = make_float2(q00, q01);
            *(float2*)(&part[wv][1][wbase]) = make_float2(q10, q11);
        }
    }
    __syncthreads();

    // ---- finalize (waves 0,1 = h): sum 8 chunk partials asc, relu, mean ----
    if (wv < 2) {
        const float bo = cbg[o];
        float r = 0.f;
        if (lane < 60) {
            float v0 = part[0][wv][wbase], v1 = part[0][wv][wbase + 1];
            #pragma unroll
            for (int q = 1; q < 8; ++q) {
                v0 += part[q][wv][wbase];
                v1 += part[q][wv][wbase + 1];
            }
            v0 += bo; v1 += bo;
            r = fmaxf(v0, 0.f) + fmaxf(v1, 0.f);
        }
        for (int off = 32; off > 0; off >>= 1) r += __shfl_xor(r, off, 64);
        if (lane == 0) msh[wv] = r * (1.0f / OUTW);
    }
    __syncthreads();

    // ---- phase D: publish msum; 10th finisher (monotonic ctr) runs the FCN ----
    if (tid == 0) {
        __hip_atomic_store(&g_msum[o * 2 + 0], msh[0], __ATOMIC_RELAXED, __HIP_MEMORY_SCOPE_AGENT);
        __hip_atomic_store(&g_msum[o * 2 + 1], msh[1], __ATOMIC_RELAXED, __HIP_MEMORY_SCOPE_AGENT);
        // ACQ_REL RMW: releases the two stores above; acquires all prior
        // blocks' releases. old%10==9 <=> 10th block of this launch (counter
        // never reset -> robust across graph replays / rocprof re-execution;
        // no spin, no deadlock).
        const unsigned old = __hip_atomic_fetch_add(&g_ctr, 1u, __ATOMIC_ACQ_REL, __HIP_MEMORY_SCOPE_AGENT);
        sflag = (old % 10u == 9u) ? 1 : 0;
    }
    __syncthreads();

    if (sflag) {   // block-uniform -> barriers inside are legal
        if (tid < 2 * NOUT)
            msums[tid] = __hip_atomic_load(&g_msum[tid], __ATOMIC_ACQUIRE, __HIP_MEMORY_SCOPE_AGENT);
        __syncthreads();
        if (tid < 64) {
            float h2v = 0.f;
            if (lane < 10) {
                float a = fcnl[200 + lane];                       // f1b
                #pragma unroll
                for (int p = 0; p < 20; ++p) a += msums[p] * fcnl[lane * 20 + p];
                h2v = 1.f / (1.f + expf(-a));
            }
            float t0 = (lane < 10) ? h2v * fcnl[210 + lane] : 0.f;   // f2w row 0
            float t1 = (lane < 10) ? h2v * fcnl[220 + lane] : 0.f;   // f2w row 1
            for (int off = 32; off > 0; off >>= 1) {
                t0 += __shfl_xor(t0, off, 64);
                t1 += __shfl_xor(t1, off, 64);
            }
            if (lane == 0) {
                const float l0 = fcnl[230] + t0, l1 = fcnl[231] + t1;
                const float m  = fmaxf(l0, l1);
                const float e0 = expf(l0 - m), e1 = expf(l1 - m);
                out[0] = e0 / (e0 + e1);
                out[1] = e1 / (e0 + e1);
            }
        }
    }
}

extern "C" void kernel_launch(void* const* d_in, const int* in_sizes, int n_in,
                              void* d_out, int out_size, void* d_ws, size_t ws_size,
                              hipStream_t stream) {
    (void)in_sizes; (void)n_in; (void)ws_size; (void)out_size; (void)d_ws;
    const float* xg  = (const float*)d_in[0];
    const float* w1  = (const float*)d_in[1];
    const float* b1  = (const float*)d_in[2];
    const float* w2  = (const float*)d_in[3];
    const float* b2  = (const float*)d_in[4];
    const float* cw  = (const float*)d_in[5];
    const float* cb  = (const float*)d_in[6];
    const float* f1w = (const float*)d_in[7];
    const float* f1b = (const float*)d_in[8];
    const float* f2w = (const float*)d_in[9];
    const float* f2b = (const float*)d_in[10];
    float* out = (float*)d_out;

    cnn_fused<<<dim3(NOUT), dim3(1024), 0, stream>>>(xg, w1, b1, w2, b2,
                                                     cw, cb, f1w, f1b, f2w, f2b, out);
}

// Round 7
// 82.154 us; speedup vs baseline: 1.0885x; 1.0885x over previous
//
#include <hip/hip_runtime.h>
#include <math.h>

#define EEG_CH 64
#define WIN    128
#define KW     9
#define OUTW   120
#define NOUT   10
#define ROWP   132          // padded LDS row stride (8B-aligned even-w float2s)
#define CWP    12           // padded cwl row stride (48B, 16B-aligned rows)

// cross-block handoff in module globals (d_ws not used):
// g_msum[o*2+h]; g_ctr = monotonic counter, 10 increments/launch (1 per block).
__device__ float        g_msum[2 * NOUT];
__device__ unsigned int g_ctr = 0;

__device__ __forceinline__ float readlane_f(float v, int l) {
    return __int_as_float(__builtin_amdgcn_readlane(__float_as_int(v), l));
}

// One fused kernel node: block o = output channel, 16 waves.
// Verified R5 structure (83.6 us): LDS staging for x/w1/w2 (R6 showed removing
// it spills SE weight registers at the 1024-thread 128-VGPR cap and regresses);
// SE chain (waves 8,9) hidden under unweighted conv dots (waves 0-7);
// FCN weights staged to LDS so the epilogue never touches cold HBM;
// tail = verified count-to-10 atomic handshake.
__launch_bounds__(1024)
__global__ void cnn_fused(const float* __restrict__ xg,
                          const float* __restrict__ w1g, const float* __restrict__ b1g,
                          const float* __restrict__ w2g, const float* __restrict__ b2g,
                          const float* __restrict__ cwg, const float* __restrict__ cbg,
                          const float* __restrict__ f1w, const float* __restrict__ f1b,
                          const float* __restrict__ f2w, const float* __restrict__ f2b,
                          float* __restrict__ out)
{
    __shared__ float w1l[64 * 64];    // transposed: w1l[i*64+j] = w1g[j*64+i]
    __shared__ float w2l[64 * 64];
    __shared__ float xl[64 * ROWP];   // eeg rows (x rows 1..64), padded
    __shared__ float cwl[64 * CWP];   // conv weights for this o, padded rows
    __shared__ float rnorm[66];
    __shared__ float nums[2];
    __shared__ float sef[128];        // se_flat [h][i]
    __shared__ float part[8][2][OUTW];// per-(chunk, h) partial pre-relu sums
    __shared__ float msh[2];
    __shared__ int   sflag;
    __shared__ float msums[2 * NOUT];
    __shared__ float fcnl[232];       // f1w[0..199] f1b[200..209] f2w[210..229] f2b[230..231]

    const int tid  = threadIdx.x;
    const int wv   = tid >> 6;        // 0..15
    const int lane = tid & 63;
    const int o    = blockIdx.x;

    // conv mapping: waves 0-7 each own an 8-channel chunk (both h)
    const int chbase = (wv & 7) * 8;

    // ---- phase A: staging + norms, spread over 16 waves ----
    // conv weights for this o -> LDS (576 floats, coalesced, padded rows)
    if (tid < 576) {
        const float v = cwg[o * (EEG_CH * KW) + tid];
        cwl[(tid / KW) * CWP + (tid % KW)] = v;
    } else if (tid < 808) {
        // FCN params -> LDS (one scalar load per thread, hidden under staging)
        const int t = tid - 576;
        float v;
        if      (t < 200) v = f1w[t];
        else if (t < 210) v = f1b[t - 200];
        else if (t < 230) v = f2w[t - 210];
        else              v = f2b[t - 230];
        fcnl[t] = v;
    }
    // eeg rows -> LDS (64 rows x 32 float4): 2 iters/thread
    for (int t = tid; t < 2048; t += 1024) {
        const int row = t >> 5, c4 = t & 31;
        const float4 v = *(const float4*)(xg + (row + 1) * WIN + c4 * 4);
        *(float4*)(xl + row * ROWP + c4 * 4) = v;
    }
    // w1/w2 transposed -> LDS (2 x 1024 float4 tasks): 2 iters/thread
    for (int t = tid; t < 2048; t += 1024) {
        const int j  = t & 63;
        const int i4 = (t >> 6) & 15;
        const float* __restrict__ src = (t < 1024) ? w1g : w2g;
        float* __restrict__ dst = (t < 1024) ? w1l : w2l;
        const float4 v = *(const float4*)(src + j * 64 + i4 * 4);
        dst[(i4 * 4 + 0) * 64 + j] = v.x;
        dst[(i4 * 4 + 1) * 64 + j] = v.y;
        dst[(i4 * 4 + 2) * 64 + j] = v.z;
        dst[(i4 * 4 + 3) * 64 + j] = v.w;
    }
    // row norms straight from global (same reduction tree as verified kernel)
    for (int row = wv; row < 66; row += 16) {
        const float v0 = xg[row * WIN + lane];
        const float v1 = xg[row * WIN + 64 + lane];
        float s = v0 * v0 + v1 * v1;
        for (int off = 32; off > 0; off >>= 1) s += __shfl_xor(s, off, 64);
        if (lane == 0) rnorm[row] = sqrtf(s);
    }
    if (wv < 2) {
        const int wrow = (wv == 0) ? 0 : 65;
        float p = xg[WIN + lane]      * xg[wrow * WIN + lane]
                + xg[WIN + 64 + lane] * xg[wrow * WIN + 64 + lane];
        for (int off = 32; off > 0; off >>= 1) p += __shfl_xor(p, off, 64);
        if (lane == 0) nums[wv] = p;
    }
    __syncthreads();

    // ---- phase B || C-dots: SE chain (waves 8,9) hidden under conv dots ----
    const int wbase = (lane < 60) ? 2 * lane : 116;   // lanes 60-63 redundant
    float p0a[8], p1a[8];
    if (wv < 8) {
        // unweighted per-channel dots (no sef dependency), identical FMA order
        #pragma unroll
        for (int ii = 0; ii < 8; ++ii) {
            const int i = chbase + ii;
            const float2* xp = (const float2*)(xl + i * ROWP + wbase);
            const float2 x0 = xp[0], x1 = xp[1], x2 = xp[2], x3 = xp[3], x4 = xp[4];
            const float xw[10] = { x0.x, x0.y, x1.x, x1.y, x2.x, x2.y,
                                   x3.x, x3.y, x4.x, x4.y };
            // weights via uniform-address LDS reads (wave-wide broadcast)
            const float4 wa = *(const float4*)(cwl + i * CWP);
            const float4 wb = *(const float4*)(cwl + i * CWP + 4);
            const float  w8 = cwl[i * CWP + 8];
            const float wk[KW] = { wa.x, wa.y, wa.z, wa.w,
                                   wb.x, wb.y, wb.z, wb.w, w8 };
            float p0 = 0.f, p1 = 0.f;
            #pragma unroll
            for (int k = 0; k < KW; ++k) {
                p0 += xw[k]     * wk[k];
                p1 += xw[k + 1] * wk[k];
            }
            p0a[ii] = p0;
            p1a[ii] = p1;
        }
    } else if (wv < 10) {
        // SE MLP for r = wv-8 (identical math to verified version)
        const int r = wv - 8, j = lane;
        const float er = nums[r] / (rnorm[j + 1] * (r == 0 ? rnorm[0] : rnorm[65]));
        float acc = b1g[j];
        #pragma unroll
        for (int i = 0; i < 64; ++i)
            acc += readlane_f(er, i) * w1l[i * 64 + j];
        const float hv = tanhf(acc);
        float acc2 = b2g[j];
        #pragma unroll
        for (int i = 0; i < 64; ++i)
            acc2 += readlane_f(hv, i) * w2l[i * 64 + j];
        const float sg = 1.f / (1.f + expf(-acc2));
        float mx = sg;
        for (int off = 32; off > 0; off >>= 1) mx = fmaxf(mx, __shfl_xor(mx, off, 64));
        const float e = expf(sg - mx);
        float ss = e;
        for (int off = 32; off > 0; off >>= 1) ss += __shfl_xor(ss, off, 64);
        sef[r * 64 + j] = e / ss;
    }
    __syncthreads();

    // ---- C2: weight dots by se (same ascending channel order), write part ----
    if (wv < 8) {
        float q00 = 0.f, q01 = 0.f;   // h=0 accumulators (pos w, w+1)
        float q10 = 0.f, q11 = 0.f;   // h=1 accumulators
        #pragma unroll
        for (int ii = 0; ii < 8; ++ii) {
            const float s0 = sef[chbase + ii];        // uniform LDS broadcast
            const float s1 = sef[64 + chbase + ii];
            q00 += s0 * p0a[ii];  q01 += s0 * p1a[ii];
            q10 += s1 * p0a[ii];  q11 += s1 * p1a[ii];
        }
        if (lane < 60) {
            *(float2*)(&part[wv][0][wbase]) = make_float2(q00, q01);
            *(float2*)(&part[wv][1][wbase]) = make_float2(q10, q11);
        }
    }
    __syncthreads();

    // ---- finalize (waves 0,1 = h): sum 8 chunk partials asc, relu, mean ----
    if (wv < 2) {
        const float bo = cbg[o];
        float r = 0.f;
        if (lane < 60) {
            float v0 = part[0][wv][wbase], v1 = part[0][wv][wbase + 1];
            #pragma unroll
            for (int q = 1; q < 8; ++q) {
                v0 += part[q][wv][wbase];
                v1 += part[q][wv][wbase + 1];
            }
            v0 += bo; v1 += bo;
            r = fmaxf(v0, 0.f) + fmaxf(v1, 0.f);
        }
        for (int off = 32; off > 0; off >>= 1) r += __shfl_xor(r, off, 64);
        if (lane == 0) msh[wv] = r * (1.0f / OUTW);
    }
    __syncthreads();

    // ---- phase D: publish msum; 10th finisher (monotonic ctr) runs the FCN ----
    if (tid == 0) {
        __hip_atomic_store(&g_msum[o * 2 + 0], msh[0], __ATOMIC_RELAXED, __HIP_MEMORY_SCOPE_AGENT);
        __hip_atomic_store(&g_msum[o * 2 + 1], msh[1], __ATOMIC_RELAXED, __HIP_MEMORY_SCOPE_AGENT);
        // ACQ_REL RMW: releases the two stores above; acquires all prior
        // blocks' releases. old%10==9 <=> 10th block of this launch (counter
        // never reset -> robust across graph replays / rocprof re-execution;
        // no spin, no deadlock).
        const unsigned old = __hip_atomic_fetch_add(&g_ctr, 1u, __ATOMIC_ACQ_REL, __HIP_MEMORY_SCOPE_AGENT);
        sflag = (old % 10u == 9u) ? 1 : 0;
    }
    __syncthreads();

    if (sflag) {   // block-uniform -> barriers inside are legal
        if (tid < 2 * NOUT)
            msums[tid] = __hip_atomic_load(&g_msum[tid], __ATOMIC_ACQUIRE, __HIP_MEMORY_SCOPE_AGENT);
        __syncthreads();
        if (tid < 64) {
            float h2v = 0.f;
            if (lane < 10) {
                float a = fcnl[200 + lane];                       // f1b
                #pragma unroll
                for (int p = 0; p < 20; ++p) a += msums[p] * fcnl[lane * 20 + p];
                h2v = 1.f / (1.f + expf(-a));
            }
            float t0 = (lane < 10) ? h2v * fcnl[210 + lane] : 0.f;   // f2w row 0
            float t1 = (lane < 10) ? h2v * fcnl[220 + lane] : 0.f;   // f2w row 1
            for (int off = 32; off > 0; off >>= 1) {
                t0 += __shfl_xor(t0, off, 64);
                t1 += __shfl_xor(t1, off, 64);
            }
            if (lane == 0) {
                const float l0 = fcnl[230] + t0, l1 = fcnl[231] + t1;
                const float m  = fmaxf(l0, l1);
                const float e0 = expf(l0 - m), e1 = expf(l1 - m);
                out[0] = e0 / (e0 + e1);
                out[1] = e1 / (e0 + e1);
            }
        }
    }
}

extern "C" void kernel_launch(void* const* d_in, const int* in_sizes, int n_in,
                              void* d_out, int out_size, void* d_ws, size_t ws_size,
                              hipStream_t stream) {
    (void)in_sizes; (void)n_in; (void)ws_size; (void)out_size; (void)d_ws;
    const float* xg  = (const float*)d_in[0];
    const float* w1  = (const float*)d_in[1];
    const float* b1  = (const float*)d_in[2];
    const float* w2  = (const float*)d_in[3];
    const float* b2  = (const float*)d_in[4];
    const float* cw  = (const float*)d_in[5];
    const float* cb  = (const float*)d_in[6];
    const float* f1w = (const float*)d_in[7];
    const float* f1b = (const float*)d_in[8];
    const float* f2w = (const float*)d_in[9];
    const float* f2b = (const float*)d_in[10];
    float* out = (float*)d_out;

    cnn_fused<<<dim3(NOUT), dim3(1024), 0, stream>>>(xg, w1, b1, w2, b2,
                                                     cw, cb, f1w, f1b, f2w, f2b, out);
}